// Round 6
// baseline (144.538 us; speedup 1.0000x reference)
//
#include <hip/hip_runtime.h>

typedef __bf16 bf16x8 __attribute__((ext_vector_type(8)));
typedef __bf16 bf16x4 __attribute__((ext_vector_type(4)));
typedef float  f32x4  __attribute__((ext_vector_type(4)));

#define NGRAPH 256
#define HDIM   256
#define DDIM   128
#define ODIM   128
#define NNODE  102400
#define NTILES 1600          // NNODE / 64
#define MLP_G  4             // graphs per mlp block
#define MLP_BLOCKS (NGRAPH / MLP_G)

// workspace layout (bytes)
#define WS_SEGX  0           // 256 KB: atomic fallback (zeroed by prep; ~never hit)
#define WS_BSW   262144      // 64 KB : swizzled bf16 W_enc
#define WS_SEG   327680      // 256 KB: final per-graph sums (written by reduce)
#define WS_PARTA 589824      // 1.6 MB: per-tile partial, graph of row 0
#define WS_PARTB 2228224     // 1.6 MB: per-tile partial, graph of row 63

// ---------------------------------------------------------------------------
// prep: zero segX + swizzle W_enc into MFMA B-fragment order (bf16).
// Bsw[((kk*16+nt)*64+lane)*8 + j] = W_enc[kk*32+quad*8+j][nt*16+m]
// ---------------------------------------------------------------------------
__global__ __launch_bounds__(256) void prep_kernel(const float* __restrict__ W_enc,
                                                   __bf16* __restrict__ Bsw,
                                                   float* __restrict__ segX) {
  int tid  = blockIdx.x * 256 + threadIdx.x;   // [0, 4096)
  float4 z = {0.f, 0.f, 0.f, 0.f};
#pragma unroll
  for (int p = 0; p < 4; ++p) ((float4*)segX)[tid + p * 4096] = z;

  int lane = tid & 63;
  int t2   = tid >> 6;
  int nt   = t2 & 15;
  int kk   = t2 >> 4;
  int quad = lane >> 4, m = lane & 15;
  int col  = nt * 16 + m;
  bf16x8 frag;
#pragma unroll
  for (int j = 0; j < 8; ++j) {
    int k   = kk * 32 + quad * 8 + j;
    frag[j] = (__bf16)W_enc[k * HDIM + col];
  }
  *(bf16x8*)(Bsw + (size_t)tid * 8) = frag;
}

// ---------------------------------------------------------------------------
// enc v6 — REGISTER-PRESSURE FIX. v5 held bfr[4][4] (64 VGPR) + acc[4][4]
// (64 AGPR, unified file!) + staging ≈ ~190 regs -> 2 waves/SIMD. Now:
// 512 threads = 8 waves, each wave owns 32 cols (2 n-tiles): acc = 32 regs;
// bfr reloaded per (kk,ntl) from Bsw (L1/L2-hot, one 16B load hidden behind
// 4 MFMAs). Target ~100 unified regs -> 5 waves/SIMD.
// Atomic-free epilogue (R5): per-tile partials partA/partB, plain stores.
// ---------------------------------------------------------------------------
__global__ __launch_bounds__(512) void enc_gemm(const float* __restrict__ x,
                                                const int* __restrict__ batch,
                                                const __bf16* __restrict__ Bsw,
                                                const float* __restrict__ b_enc,
                                                float* __restrict__ partA,
                                                float* __restrict__ partB,
                                                float* __restrict__ segX) {
  __shared__ __align__(16) __bf16 Albuf[64 * 136];
  __shared__ int gbuf[64];
  const int    t    = threadIdx.x;
  const int    tile = blockIdx.x;
  const size_t base = (size_t)tile * 64;

  const int lane = t & 63, wave = t >> 6;   // wave in [0,8)
  const int m = lane & 15, quad = lane >> 4;

  // stage 64x128 fp32 -> bf16 into LDS (coalesced; 4 float4 per thread)
  const float4* xsrc = (const float4*)(x + base * DDIM);
#pragma unroll
  for (int p = 0; p < 4; ++p) {
    int    i   = t + p * 512;          // float4 index; 32 per row
    float4 v   = xsrc[i];
    int    row = i >> 5, c4 = i & 31;
    bf16x4 bv;
    bv[0] = (__bf16)v.x; bv[1] = (__bf16)v.y;
    bv[2] = (__bf16)v.z; bv[3] = (__bf16)v.w;
    *(bf16x4*)&Albuf[row * 136 + c4 * 4] = bv;
  }
  if (t < 64) gbuf[t] = batch[base + t];
  __syncthreads();

  float bias[2];
#pragma unroll
  for (int ntl = 0; ntl < 2; ++ntl) bias[ntl] = b_enc[(wave * 2 + ntl) * 16 + m];

  f32x4 acc[2][4];   // [ntl][mt] — 32 regs
#pragma unroll
  for (int a = 0; a < 2; ++a)
#pragma unroll
    for (int b = 0; b < 4; ++b) acc[a][b] = (f32x4){0.f, 0.f, 0.f, 0.f};

#pragma unroll
  for (int kk = 0; kk < 4; ++kk) {
    bf16x8 afr[4];
#pragma unroll
    for (int mt = 0; mt < 4; ++mt)
      afr[mt] = *(const bf16x8*)&Albuf[(mt * 16 + m) * 136 + kk * 32 + quad * 8];
#pragma unroll
    for (int ntl = 0; ntl < 2; ++ntl) {
      bf16x8 bfr =
          *(const bf16x8*)(Bsw + (size_t)(((kk * 16 + wave * 2 + ntl) * 64) + lane) * 8);
#pragma unroll
      for (int mt = 0; mt < 4; ++mt)
        acc[ntl][mt] = __builtin_amdgcn_mfma_f32_16x16x32_bf16(
            afr[mt], bfr, acc[ntl][mt], 0, 0, 0);
    }
  }

  // ---- epilogue: relu+bias, split rows by graph, plain-store partials ----
  const int  g0  = gbuf[0], g63 = gbuf[63];
  const bool uni = (g0 == g63);

  int gl[16];
  if (!uni) {
#pragma unroll
    for (int mt = 0; mt < 4; ++mt)
#pragma unroll
      for (int r = 0; r < 4; ++r) gl[mt * 4 + r] = gbuf[mt * 16 + quad * 4 + r];
  }

#pragma unroll
  for (int ntl = 0; ntl < 2; ++ntl) {
    const int col = (wave * 2 + ntl) * 16 + m;
    float sA = 0.f, sB = 0.f;
    if (uni) {
#pragma unroll
      for (int mt = 0; mt < 4; ++mt)
#pragma unroll
        for (int r = 0; r < 4; ++r)
          sA += fmaxf(acc[ntl][mt][r] + bias[ntl], 0.f);
    } else {
#pragma unroll
      for (int mt = 0; mt < 4; ++mt)
#pragma unroll
        for (int r = 0; r < 4; ++r) {
          int   g = gl[mt * 4 + r];
          float v = fmaxf(acc[ntl][mt][r] + bias[ntl], 0.f);
          if (g == g0)       sA += v;
          else if (g == g63) sB += v;
          else atomicAdd(&segX[g * HDIM + col], v);   // ~never taken
        }
    }
    sA += __shfl_xor(sA, 16, 64);
    sA += __shfl_xor(sA, 32, 64);
    sB += __shfl_xor(sB, 16, 64);
    sB += __shfl_xor(sB, 32, 64);
    if (quad == 0) {
      partA[(size_t)tile * HDIM + col] = sA;
      partB[(size_t)tile * HDIM + col] = sB;
    }
  }
}

// ---------------------------------------------------------------------------
// reduce: one block per graph; binary-search batch for the graph's tile range,
// sum partials. ~7 tiles per graph.
// ---------------------------------------------------------------------------
__global__ __launch_bounds__(256) void reduce_kernel(const int* __restrict__ batch,
                                                     const float* __restrict__ partA,
                                                     const float* __restrict__ partB,
                                                     const float* __restrict__ segX,
                                                     float* __restrict__ seg) {
  const int g = blockIdx.x, c = threadIdx.x;

  int lo = 0, hi = NNODE;                 // lower_bound(batch, g)
  while (lo < hi) { int mid = (lo + hi) >> 1; if (batch[mid] < g) lo = mid + 1; else hi = mid; }
  const int start = lo;
  hi = NNODE;                             // lower_bound(batch, g+1)
  while (lo < hi) { int mid = (lo + hi) >> 1; if (batch[mid] < g + 1) lo = mid + 1; else hi = mid; }
  const int end = lo;

  float s = segX[g * HDIM + c];
  if (end > start) {
    const int t0 = start >> 6, t1 = (end - 1) >> 6;
    for (int t = t0; t <= t1; ++t) {
      if (batch[t * 64] == g)      s += partA[(size_t)t * HDIM + c];
      if (batch[t * 64 + 63] == g) s += partB[(size_t)t * HDIM + c];
    }
  }
  seg[g * HDIM + c] = s;
}

// ---------------------------------------------------------------------------
// mlp v6 — AGGREGATE-TRAFFIC FIX. 4 graphs per block, 64 blocks: each weight
// float4 is loaded once and FMA'd into 4 graphs' accumulators -> total weight
// traffic 229 MB -> 57 MB. Per 256-wide layer: 512 thr = 8 k-chunks x 64
// col-quads; partials part[8][G][256]; reduction order r=0..7 identical to v5
// -> bitwise-identical fp32 results.
// ---------------------------------------------------------------------------
__device__ __forceinline__ void mlp_layerG(const float (*__restrict__ bin)[HDIM],
                                           float (*__restrict__ bout)[HDIM],
                                           float (*__restrict__ part)[MLP_G][HDIM],
                                           const float* __restrict__ W,
                                           const float* __restrict__ bias,
                                           bool relu, int t) {
  const int w  = t >> 6;          // k-chunk [0,8)
  const int jq = t & 63;          // col quad
  f32x4 acc[MLP_G];
#pragma unroll
  for (int g = 0; g < MLP_G; ++g) acc[g] = (f32x4){0.f, 0.f, 0.f, 0.f};
  const float4* wrow = (const float4*)(W + (size_t)w * 32 * HDIM) + jq;
#pragma unroll 4
  for (int k = 0; k < 32; ++k) {
    float4 ww = wrow[(size_t)k * (HDIM / 4)];
#pragma unroll
    for (int g = 0; g < MLP_G; ++g) {
      float a = bin[g][w * 32 + k];        // wave-uniform LDS broadcast
      acc[g][0] += a * ww.x; acc[g][1] += a * ww.y;
      acc[g][2] += a * ww.z; acc[g][3] += a * ww.w;
    }
  }
#pragma unroll
  for (int g = 0; g < MLP_G; ++g) *(f32x4*)&part[w][g][jq * 4] = acc[g];
  __syncthreads();
#pragma unroll
  for (int p = 0; p < 2; ++p) {
    int g = (t >> 8) + p * 2, c = t & 255;
    float v = 0.f;
#pragma unroll
    for (int r = 0; r < 8; ++r) v += part[r][g][c];
    v += bias[c];
    if (relu) v = fmaxf(v, 0.f);
    bout[g][c] = v;
  }
  __syncthreads();
}

__global__ __launch_bounds__(512) void mlp_kernel(
    const float* __restrict__ seg,
    const float* __restrict__ Wv1, const float* __restrict__ bv1,
    const float* __restrict__ Wv2, const float* __restrict__ bv2,
    const float* __restrict__ Wp1, const float* __restrict__ bp1,
    const float* __restrict__ Wp2, const float* __restrict__ bp2,
    float* __restrict__ out) {
  __shared__ __align__(16) float bufA[MLP_G][HDIM];
  __shared__ __align__(16) float bufB[MLP_G][HDIM];
  __shared__ __align__(16) float part[8][MLP_G][HDIM];   // 32 KB
  const int t  = threadIdx.x;
  const int gb = blockIdx.x * MLP_G;

#pragma unroll
  for (int p = 0; p < 2; ++p) {
    int idx = t + p * 512;               // [0, 1024)
    int g = idx >> 8, c = idx & 255;
    bufA[g][c] = seg[(gb + g) * HDIM + c] * 0.125f;
  }
  __syncthreads();

  mlp_layerG(bufA, bufB, part, Wv1, bv1, true,  t);
  mlp_layerG(bufB, bufA, part, Wv2, bv2, false, t);
  mlp_layerG(bufA, bufB, part, Wp1, bp1, true,  t);

  // layer 4: out = bufB @ Wp2 + bp2 (O=128). 16 k-chunks x 32 col-quads.
  {
    const int w  = t >> 5;               // [0,16)
    const int jq = t & 31;               // [0,32)
    f32x4 acc[MLP_G];
#pragma unroll
    for (int g = 0; g < MLP_G; ++g) acc[g] = (f32x4){0.f, 0.f, 0.f, 0.f};
    const float4* wrow = (const float4*)(Wp2 + (size_t)w * 16 * ODIM) + jq;
#pragma unroll 4
    for (int k = 0; k < 16; ++k) {
      float4 ww = wrow[(size_t)k * (ODIM / 4)];
#pragma unroll
      for (int g = 0; g < MLP_G; ++g) {
        float a = bufB[g][w * 16 + k];
        acc[g][0] += a * ww.x; acc[g][1] += a * ww.y;
        acc[g][2] += a * ww.z; acc[g][3] += a * ww.w;
      }
    }
    float (*p16)[MLP_G][ODIM] = (float (*)[MLP_G][ODIM])part;  // 16x4x128
#pragma unroll
    for (int g = 0; g < MLP_G; ++g) *(f32x4*)&p16[w][g][jq * 4] = acc[g];
    __syncthreads();
    {
      int g = t >> 7, c = t & 127;       // 512 outputs, one per thread
      float v = bp2[c];
#pragma unroll
      for (int r = 0; r < 16; ++r) v += p16[r][g][c];
      out[(gb + g) * ODIM + c] = v;
    }
  }
}

// ---------------------------------------------------------------------------
extern "C" void kernel_launch(void* const* d_in, const int* in_sizes, int n_in,
                              void* d_out, int out_size, void* d_ws, size_t ws_size,
                              hipStream_t stream) {
  const float* x     = (const float*)d_in[0];
  // d_in[1] = edge_index : unused by the reference
  const int*   batch = (const int*)d_in[2];
  const float* W_enc = (const float*)d_in[3];
  const float* b_enc = (const float*)d_in[4];
  const float* W_v1  = (const float*)d_in[5];
  const float* b_v1  = (const float*)d_in[6];
  const float* W_v2  = (const float*)d_in[7];
  const float* b_v2  = (const float*)d_in[8];
  const float* W_p1  = (const float*)d_in[9];
  const float* b_p1  = (const float*)d_in[10];
  const float* W_p2  = (const float*)d_in[11];
  const float* b_p2  = (const float*)d_in[12];
  float* out = (float*)d_out;

  float*  segX  = (float*)((char*)d_ws + WS_SEGX);
  __bf16* Bsw   = (__bf16*)((char*)d_ws + WS_BSW);
  float*  seg   = (float*)((char*)d_ws + WS_SEG);
  float*  partA = (float*)((char*)d_ws + WS_PARTA);
  float*  partB = (float*)((char*)d_ws + WS_PARTB);

  prep_kernel<<<16, 256, 0, stream>>>(W_enc, Bsw, segX);
  enc_gemm<<<NTILES, 512, 0, stream>>>(x, batch, Bsw, b_enc, partA, partB, segX);
  reduce_kernel<<<NGRAPH, 256, 0, stream>>>(batch, partA, partB, segX, seg);
  mlp_kernel<<<MLP_BLOCKS, 512, 0, stream>>>(seg, W_v1, b_v1, W_v2, b_v2,
                                             W_p1, b_p1, W_p2, b_p2, out);
}

// Round 7
// 134.442 us; speedup vs baseline: 1.0751x; 1.0751x over previous
//
#include <hip/hip_runtime.h>

typedef __bf16 bf16x8 __attribute__((ext_vector_type(8)));
typedef __bf16 bf16x4 __attribute__((ext_vector_type(4)));
typedef float  f32x4  __attribute__((ext_vector_type(4)));

#define NGRAPH 256
#define HDIM   256
#define DDIM   128
#define ODIM   128
#define NNODE  102400
#define NTILES 1600          // NNODE / 64

// workspace layout (bytes)
#define WS_SEGX  0           // 256 KB: atomic fallback (zeroed by prep; ~never hit)
#define WS_BSW   262144      // 64 KB : swizzled bf16 W_enc
#define WS_FIRST 327680      // 1 KB  : first node index per graph (-1 if empty)
#define WS_LAST  328704      // 1 KB  : last node index per graph
#define WS_PARTA 589824      // 1.6 MB: per-tile partial, graph of row 0
#define WS_PARTB 2228224     // 1.6 MB: per-tile partial, graph of row 63

// ---------------------------------------------------------------------------
// prep v2: coalesced. Grid = 4 blocks (one per kk). Stage W_enc rows
// [kk*32, kk*32+32) into LDS with float4 coalesced loads, then emit the MFMA
// B-fragment swizzle: Bsw[((kk*16+nt)*64+lane)*8+j] = W_enc[kk*32+quad*8+j][nt*16+m].
// Also zeroes segX and inits first[] = -1 (block 0).
// ---------------------------------------------------------------------------
__global__ __launch_bounds__(256) void prep_kernel(const float* __restrict__ W_enc,
                                                   __bf16* __restrict__ Bsw,
                                                   float* __restrict__ segX,
                                                   int* __restrict__ first) {
  __shared__ float wtile[32][256];
  const int t = threadIdx.x, kk = blockIdx.x;
  const int tid = kk * 256 + t;

  float4 z = {0.f, 0.f, 0.f, 0.f};
#pragma unroll
  for (int p = 0; p < 16; ++p) ((float4*)segX)[tid + p * 1024] = z;
  if (kk == 0) first[t] = -1;

  const float4* src = (const float4*)(W_enc + (size_t)kk * 32 * HDIM);
#pragma unroll
  for (int i = 0; i < 8; ++i) {
    int    idx = t + i * 256;          // [0,2048) float4
    float4 v   = src[idx];
    int    row = idx >> 6, c4 = idx & 63;
    *(float4*)&wtile[row][c4 * 4] = v;
  }
  __syncthreads();

#pragma unroll
  for (int j = 0; j < 4; ++j) {
    int f = t + j * 256;               // [0,1024) = nt*64 + lane
    int lane = f & 63, nt = f >> 6;
    int quad = lane >> 4, m = lane & 15, col = nt * 16 + m;
    bf16x8 frag;
#pragma unroll
    for (int jj = 0; jj < 8; ++jj) frag[jj] = (__bf16)wtile[quad * 8 + jj][col];
    *(bf16x8*)(Bsw + (size_t)(((kk * 16 + nt) * 64) + lane) * 8) = frag;
  }
}

// ---------------------------------------------------------------------------
// bound: mark each graph's first/last node index (batch is sorted).
// Coalesced; replaces reduce's 2x17 serially-dependent binary-search loads.
// ---------------------------------------------------------------------------
__global__ __launch_bounds__(1024) void bound_kernel(const int* __restrict__ batch,
                                                     int* __restrict__ first,
                                                     int* __restrict__ last) {
  const int i = blockIdx.x * 1024 + threadIdx.x;
  const int b = batch[i];
  if (i == 0 || batch[i - 1] != b) first[b] = i;
  if (i == NNODE - 1 || batch[i + 1] != b) last[b] = i;
}

// ---------------------------------------------------------------------------
// enc (v6, unchanged): 512 thr = 8 waves x 32 cols. LDS-staged bf16 A-tile,
// Bsw B-fragments reloaded per (kk,ntl), atomic-free partial epilogue.
// ---------------------------------------------------------------------------
__global__ __launch_bounds__(512) void enc_gemm(const float* __restrict__ x,
                                                const int* __restrict__ batch,
                                                const __bf16* __restrict__ Bsw,
                                                const float* __restrict__ b_enc,
                                                float* __restrict__ partA,
                                                float* __restrict__ partB,
                                                float* __restrict__ segX) {
  __shared__ __align__(16) __bf16 Albuf[64 * 136];
  __shared__ int gbuf[64];
  const int    t    = threadIdx.x;
  const int    tile = blockIdx.x;
  const size_t base = (size_t)tile * 64;

  const int lane = t & 63, wave = t >> 6;
  const int m = lane & 15, quad = lane >> 4;

  const float4* xsrc = (const float4*)(x + base * DDIM);
#pragma unroll
  for (int p = 0; p < 4; ++p) {
    int    i   = t + p * 512;
    float4 v   = xsrc[i];
    int    row = i >> 5, c4 = i & 31;
    bf16x4 bv;
    bv[0] = (__bf16)v.x; bv[1] = (__bf16)v.y;
    bv[2] = (__bf16)v.z; bv[3] = (__bf16)v.w;
    *(bf16x4*)&Albuf[row * 136 + c4 * 4] = bv;
  }
  if (t < 64) gbuf[t] = batch[base + t];
  __syncthreads();

  float bias[2];
#pragma unroll
  for (int ntl = 0; ntl < 2; ++ntl) bias[ntl] = b_enc[(wave * 2 + ntl) * 16 + m];

  f32x4 acc[2][4];
#pragma unroll
  for (int a = 0; a < 2; ++a)
#pragma unroll
    for (int b = 0; b < 4; ++b) acc[a][b] = (f32x4){0.f, 0.f, 0.f, 0.f};

#pragma unroll
  for (int kk = 0; kk < 4; ++kk) {
    bf16x8 afr[4];
#pragma unroll
    for (int mt = 0; mt < 4; ++mt)
      afr[mt] = *(const bf16x8*)&Albuf[(mt * 16 + m) * 136 + kk * 32 + quad * 8];
#pragma unroll
    for (int ntl = 0; ntl < 2; ++ntl) {
      bf16x8 bfr =
          *(const bf16x8*)(Bsw + (size_t)(((kk * 16 + wave * 2 + ntl) * 64) + lane) * 8);
#pragma unroll
      for (int mt = 0; mt < 4; ++mt)
        acc[ntl][mt] = __builtin_amdgcn_mfma_f32_16x16x32_bf16(
            afr[mt], bfr, acc[ntl][mt], 0, 0, 0);
    }
  }

  const int  g0  = gbuf[0], g63 = gbuf[63];
  const bool uni = (g0 == g63);

  int gl[16];
  if (!uni) {
#pragma unroll
    for (int mt = 0; mt < 4; ++mt)
#pragma unroll
      for (int r = 0; r < 4; ++r) gl[mt * 4 + r] = gbuf[mt * 16 + quad * 4 + r];
  }

#pragma unroll
  for (int ntl = 0; ntl < 2; ++ntl) {
    const int col = (wave * 2 + ntl) * 16 + m;
    float sA = 0.f, sB = 0.f;
    if (uni) {
#pragma unroll
      for (int mt = 0; mt < 4; ++mt)
#pragma unroll
        for (int r = 0; r < 4; ++r)
          sA += fmaxf(acc[ntl][mt][r] + bias[ntl], 0.f);
    } else {
#pragma unroll
      for (int mt = 0; mt < 4; ++mt)
#pragma unroll
        for (int r = 0; r < 4; ++r) {
          int   g = gl[mt * 4 + r];
          float v = fmaxf(acc[ntl][mt][r] + bias[ntl], 0.f);
          if (g == g0)       sA += v;
          else if (g == g63) sB += v;
          else atomicAdd(&segX[g * HDIM + col], v);   // ~never taken
        }
    }
    sA += __shfl_xor(sA, 16, 64);
    sA += __shfl_xor(sA, 32, 64);
    sB += __shfl_xor(sB, 16, 64);
    sB += __shfl_xor(sB, 32, 64);
    if (quad == 0) {
      partA[(size_t)tile * HDIM + col] = sA;
      partB[(size_t)tile * HDIM + col] = sB;
    }
  }
}

// ---------------------------------------------------------------------------
// mlp (fused reduce): 256 blocks x 512 thr, 1 graph/block (known-best shape).
// Phase 0: assemble seg row g from partials via first/last tables (identical
// summation order to the old reduce kernel -> bitwise-same results).
// Layers: v5 structure (8 k-chunks x 32, LDS partials, register biases).
// ---------------------------------------------------------------------------
__device__ __forceinline__ void mlp_layer256(const float* __restrict__ buf_in,
                                             float* __restrict__ buf_out,
                                             float* __restrict__ part,  // [8][256]
                                             const float* __restrict__ W,
                                             float bias_t, bool relu, int t) {
  const int w  = t >> 6;
  const int jq = t & 63;
  f32x4 acc = {0.f, 0.f, 0.f, 0.f};
  const float4* wrow = (const float4*)(W + (size_t)w * 32 * HDIM) + jq;
#pragma unroll 8
  for (int k = 0; k < 32; ++k) {
    float  a  = buf_in[w * 32 + k];
    float4 ww = wrow[(size_t)k * (HDIM / 4)];
    acc[0] += a * ww.x; acc[1] += a * ww.y;
    acc[2] += a * ww.z; acc[3] += a * ww.w;
  }
  *(f32x4*)&part[w * HDIM + jq * 4] = acc;
  __syncthreads();
  if (t < HDIM) {
    float v = 0.f;
#pragma unroll
    for (int r = 0; r < 8; ++r) v += part[r * HDIM + t];
    v += bias_t;
    if (relu) v = fmaxf(v, 0.f);
    buf_out[t] = v;
  }
  __syncthreads();
}

__global__ __launch_bounds__(512) void mlp_kernel(
    const int* __restrict__ batch,
    const float* __restrict__ partA, const float* __restrict__ partB,
    const float* __restrict__ segX,
    const int* __restrict__ first, const int* __restrict__ last,
    const float* __restrict__ Wv1, const float* __restrict__ bv1,
    const float* __restrict__ Wv2, const float* __restrict__ bv2,
    const float* __restrict__ Wp1, const float* __restrict__ bp1,
    const float* __restrict__ Wp2, const float* __restrict__ bp2,
    float* __restrict__ out) {
  __shared__ __align__(16) float bufA[HDIM];
  __shared__ __align__(16) float bufB[HDIM];
  __shared__ __align__(16) float part[8 * HDIM];  // viewed as [16][128] in L4
  const int t = threadIdx.x;
  const int g = blockIdx.x;

  float myb1 = 0.f, myb2 = 0.f, myb3 = 0.f, myb4 = 0.f;
  if (t < HDIM) {
    myb1 = bv1[t]; myb2 = bv2[t]; myb3 = bp1[t];
    // fused reduce: same order as old reduce_kernel (segX, then tiles asc,
    // partA before partB per tile)
    float s = segX[g * HDIM + t];
    int   f = first[g];
    if (f >= 0) {
      const int t0 = f >> 6, t1 = last[g] >> 6;
      for (int tl = t0; tl <= t1; ++tl) {
        if (batch[tl * 64] == g)      s += partA[(size_t)tl * HDIM + t];
        if (batch[tl * 64 + 63] == g) s += partB[(size_t)tl * HDIM + t];
      }
    }
    bufA[t] = s * 0.125f;
  }
  if (t < ODIM) myb4 = bp2[t];
  __syncthreads();

  mlp_layer256(bufA, bufB, part, Wv1, myb1, true,  t);
  mlp_layer256(bufB, bufA, part, Wv2, myb2, false, t);
  mlp_layer256(bufA, bufB, part, Wp1, myb3, true,  t);

  {
    const int w  = t >> 5;
    const int jq = t & 31;
    f32x4 acc = {0.f, 0.f, 0.f, 0.f};
    const float4* wrow = (const float4*)(Wp2 + (size_t)w * 16 * ODIM) + jq;
#pragma unroll 8
    for (int k = 0; k < 16; ++k) {
      float  a  = bufB[w * 16 + k];
      float4 ww = wrow[(size_t)k * (ODIM / 4)];
      acc[0] += a * ww.x; acc[1] += a * ww.y;
      acc[2] += a * ww.z; acc[3] += a * ww.w;
    }
    *(f32x4*)&part[w * ODIM + jq * 4] = acc;
    __syncthreads();
    if (t < ODIM) {
      float v = myb4;
#pragma unroll
      for (int r = 0; r < 16; ++r) v += part[r * ODIM + t];
      out[g * ODIM + t] = v;
    }
  }
}

// ---------------------------------------------------------------------------
extern "C" void kernel_launch(void* const* d_in, const int* in_sizes, int n_in,
                              void* d_out, int out_size, void* d_ws, size_t ws_size,
                              hipStream_t stream) {
  const float* x     = (const float*)d_in[0];
  // d_in[1] = edge_index : unused by the reference
  const int*   batch = (const int*)d_in[2];
  const float* W_enc = (const float*)d_in[3];
  const float* b_enc = (const float*)d_in[4];
  const float* W_v1  = (const float*)d_in[5];
  const float* b_v1  = (const float*)d_in[6];
  const float* W_v2  = (const float*)d_in[7];
  const float* b_v2  = (const float*)d_in[8];
  const float* W_p1  = (const float*)d_in[9];
  const float* b_p1  = (const float*)d_in[10];
  const float* W_p2  = (const float*)d_in[11];
  const float* b_p2  = (const float*)d_in[12];
  float* out = (float*)d_out;

  float*  segX  = (float*)((char*)d_ws + WS_SEGX);
  __bf16* Bsw   = (__bf16*)((char*)d_ws + WS_BSW);
  int*    first = (int*)((char*)d_ws + WS_FIRST);
  int*    last  = (int*)((char*)d_ws + WS_LAST);
  float*  partA = (float*)((char*)d_ws + WS_PARTA);
  float*  partB = (float*)((char*)d_ws + WS_PARTB);

  prep_kernel<<<4, 256, 0, stream>>>(W_enc, Bsw, segX, first);
  bound_kernel<<<100, 1024, 0, stream>>>(batch, first, last);
  enc_gemm<<<NTILES, 512, 0, stream>>>(x, batch, Bsw, b_enc, partA, partB, segX);
  mlp_kernel<<<NGRAPH, 512, 0, stream>>>(batch, partA, partB, segX, first, last,
                                         W_v1, b_v1, W_v2, b_v2,
                                         W_p1, b_p1, W_p2, b_p2, out);
}

// Round 8
// 134.324 us; speedup vs baseline: 1.0760x; 1.0009x over previous
//
#include <hip/hip_runtime.h>

typedef __bf16 bf16x8 __attribute__((ext_vector_type(8)));
typedef __bf16 bf16x4 __attribute__((ext_vector_type(4)));
typedef float  f32x4  __attribute__((ext_vector_type(4)));

#define NGRAPH 256
#define HDIM   256
#define DDIM   128
#define ODIM   128
#define NNODE  102400
#define NTILES 1600          // NNODE / 64

// workspace layout (bytes)
#define WS_SEGX  0           // 256 KB: atomic fallback (zeroed by prep; ~never hit)
#define WS_BSW   262144      // 64 KB : swizzled bf16 W_enc
#define WS_FIRST 327680      // 1 KB  : first node index per graph (-1 if empty)
#define WS_LAST  328704      // 1 KB  : last node index per graph
#define WS_PARTA 589824      // 1.6 MB: per-tile partial, graph of row 0
#define WS_PARTB 2228224     // 1.6 MB: per-tile partial, graph of row 63

// ---------------------------------------------------------------------------
// prep v2 (unchanged): coalesced swizzle of W_enc into MFMA B-fragment order;
// zeroes segX; inits first[] = -1.
// ---------------------------------------------------------------------------
__global__ __launch_bounds__(256) void prep_kernel(const float* __restrict__ W_enc,
                                                   __bf16* __restrict__ Bsw,
                                                   float* __restrict__ segX,
                                                   int* __restrict__ first) {
  __shared__ float wtile[32][256];
  const int t = threadIdx.x, kk = blockIdx.x;
  const int tid = kk * 256 + t;

  float4 z = {0.f, 0.f, 0.f, 0.f};
#pragma unroll
  for (int p = 0; p < 16; ++p) ((float4*)segX)[tid + p * 1024] = z;
  if (kk == 0) first[t] = -1;

  const float4* src = (const float4*)(W_enc + (size_t)kk * 32 * HDIM);
#pragma unroll
  for (int i = 0; i < 8; ++i) {
    int    idx = t + i * 256;
    float4 v   = src[idx];
    int    row = idx >> 6, c4 = idx & 63;
    *(float4*)&wtile[row][c4 * 4] = v;
  }
  __syncthreads();

#pragma unroll
  for (int j = 0; j < 4; ++j) {
    int f = t + j * 256;
    int lane = f & 63, nt = f >> 6;
    int quad = lane >> 4, m = lane & 15, col = nt * 16 + m;
    bf16x8 frag;
#pragma unroll
    for (int jj = 0; jj < 8; ++jj) frag[jj] = (__bf16)wtile[quad * 8 + jj][col];
    *(bf16x8*)(Bsw + (size_t)(((kk * 16 + nt) * 64) + lane) * 8) = frag;
  }
}

// ---------------------------------------------------------------------------
// bound (unchanged): mark each graph's first/last node index.
// ---------------------------------------------------------------------------
__global__ __launch_bounds__(1024) void bound_kernel(const int* __restrict__ batch,
                                                     int* __restrict__ first,
                                                     int* __restrict__ last) {
  const int i = blockIdx.x * 1024 + threadIdx.x;
  const int b = batch[i];
  if (i == 0 || batch[i - 1] != b) first[b] = i;
  if (i == NNODE - 1 || batch[i + 1] != b) last[b] = i;
}

// ---------------------------------------------------------------------------
// enc v8 — COUNTER-DOMAIN SEPARATION. All 8 B-fragments hoisted to block
// start (32 VGPRs, global loads overlap the staging loads); the MFMA K-loop
// then touches ONLY LDS + MFMA, the compiler's proven fine-grained-lgkmcnt
// case — no per-ntl vmcnt waits inside the compute phase.
// ---------------------------------------------------------------------------
__global__ __launch_bounds__(512) void enc_gemm(const float* __restrict__ x,
                                                const int* __restrict__ batch,
                                                const __bf16* __restrict__ Bsw,
                                                const float* __restrict__ b_enc,
                                                float* __restrict__ partA,
                                                float* __restrict__ partB,
                                                float* __restrict__ segX) {
  __shared__ __align__(16) __bf16 Albuf[64 * 136];
  __shared__ int gbuf[64];
  const int    t    = threadIdx.x;
  const int    tile = blockIdx.x;
  const size_t base = (size_t)tile * 64;

  const int lane = t & 63, wave = t >> 6;   // wave in [0,8)
  const int m = lane & 15, quad = lane >> 4;

  // hoisted B fragments: [kk][ntl] — 8 x 16B global loads, 32 VGPRs
  bf16x8 bfrr[4][2];
#pragma unroll
  for (int kk = 0; kk < 4; ++kk)
#pragma unroll
    for (int ntl = 0; ntl < 2; ++ntl)
      bfrr[kk][ntl] =
          *(const bf16x8*)(Bsw + (size_t)(((kk * 16 + wave * 2 + ntl) * 64) + lane) * 8);

  float bias[2];
#pragma unroll
  for (int ntl = 0; ntl < 2; ++ntl) bias[ntl] = b_enc[(wave * 2 + ntl) * 16 + m];

  // stage 64x128 fp32 -> bf16 into LDS (coalesced; 4 float4 per thread)
  const float4* xsrc = (const float4*)(x + base * DDIM);
#pragma unroll
  for (int p = 0; p < 4; ++p) {
    int    i   = t + p * 512;
    float4 v   = xsrc[i];
    int    row = i >> 5, c4 = i & 31;
    bf16x4 bv;
    bv[0] = (__bf16)v.x; bv[1] = (__bf16)v.y;
    bv[2] = (__bf16)v.z; bv[3] = (__bf16)v.w;
    *(bf16x4*)&Albuf[row * 136 + c4 * 4] = bv;
  }
  if (t < 64) gbuf[t] = batch[base + t];
  __syncthreads();

  f32x4 acc[2][4];   // [ntl][mt] — 32 regs
#pragma unroll
  for (int a = 0; a < 2; ++a)
#pragma unroll
    for (int b = 0; b < 4; ++b) acc[a][b] = (f32x4){0.f, 0.f, 0.f, 0.f};

  // pure LDS + MFMA phase
#pragma unroll
  for (int kk = 0; kk < 4; ++kk) {
    bf16x8 afr[4];
#pragma unroll
    for (int mt = 0; mt < 4; ++mt)
      afr[mt] = *(const bf16x8*)&Albuf[(mt * 16 + m) * 136 + kk * 32 + quad * 8];
#pragma unroll
    for (int ntl = 0; ntl < 2; ++ntl)
#pragma unroll
      for (int mt = 0; mt < 4; ++mt)
        acc[ntl][mt] = __builtin_amdgcn_mfma_f32_16x16x32_bf16(
            afr[mt], bfrr[kk][ntl], acc[ntl][mt], 0, 0, 0);
  }

  // ---- epilogue: relu+bias, split rows by graph, plain-store partials ----
  const int  g0  = gbuf[0], g63 = gbuf[63];
  const bool uni = (g0 == g63);

  int gl[16];
  if (!uni) {
#pragma unroll
    for (int mt = 0; mt < 4; ++mt)
#pragma unroll
      for (int r = 0; r < 4; ++r) gl[mt * 4 + r] = gbuf[mt * 16 + quad * 4 + r];
  }

#pragma unroll
  for (int ntl = 0; ntl < 2; ++ntl) {
    const int col = (wave * 2 + ntl) * 16 + m;
    float sA = 0.f, sB = 0.f;
    if (uni) {
#pragma unroll
      for (int mt = 0; mt < 4; ++mt)
#pragma unroll
        for (int r = 0; r < 4; ++r)
          sA += fmaxf(acc[ntl][mt][r] + bias[ntl], 0.f);
    } else {
#pragma unroll
      for (int mt = 0; mt < 4; ++mt)
#pragma unroll
        for (int r = 0; r < 4; ++r) {
          int   g = gl[mt * 4 + r];
          float v = fmaxf(acc[ntl][mt][r] + bias[ntl], 0.f);
          if (g == g0)       sA += v;
          else if (g == g63) sB += v;
          else atomicAdd(&segX[g * HDIM + col], v);   // ~never taken
        }
    }
    sA += __shfl_xor(sA, 16, 64);
    sA += __shfl_xor(sA, 32, 64);
    sB += __shfl_xor(sB, 16, 64);
    sB += __shfl_xor(sB, 32, 64);
    if (quad == 0) {
      partA[(size_t)tile * HDIM + col] = sA;
      partB[(size_t)tile * HDIM + col] = sB;
    }
  }
}

// ---------------------------------------------------------------------------
// mlp v8 — COUNTER-DOMAIN SEPARATION. Each wave's 32-float a-chunk is
// preloaded into 8 f32x4 registers (one lgkm wait), so the unrolled k-loop
// is pure global-load + fmac: 32 loads pipeline freely under vmcnt only.
// Structure/summation order identical to v7 -> bitwise-same results.
// ---------------------------------------------------------------------------
__device__ __forceinline__ void mlp_layer256(const float* __restrict__ buf_in,
                                             float* __restrict__ buf_out,
                                             float* __restrict__ part,  // [8][256]
                                             const float* __restrict__ W,
                                             float bias_t, bool relu, int t) {
  const int w  = t >> 6;
  const int jq = t & 63;
  f32x4 av[8];                           // the wave's 32 a-values, registers
#pragma unroll
  for (int i = 0; i < 8; ++i) av[i] = *(const f32x4*)&buf_in[w * 32 + i * 4];
  f32x4 acc = {0.f, 0.f, 0.f, 0.f};
  const float4* wrow = (const float4*)(W + (size_t)w * 32 * HDIM) + jq;
#pragma unroll
  for (int k = 0; k < 32; ++k) {
    float  a  = av[k >> 2][k & 3];
    float4 ww = wrow[(size_t)k * (HDIM / 4)];
    acc[0] += a * ww.x; acc[1] += a * ww.y;
    acc[2] += a * ww.z; acc[3] += a * ww.w;
  }
  *(f32x4*)&part[w * HDIM + jq * 4] = acc;
  __syncthreads();
  if (t < HDIM) {
    float v = 0.f;
#pragma unroll
    for (int r = 0; r < 8; ++r) v += part[r * HDIM + t];
    v += bias_t;
    if (relu) v = fmaxf(v, 0.f);
    buf_out[t] = v;
  }
  __syncthreads();
}

__global__ __launch_bounds__(512) void mlp_kernel(
    const int* __restrict__ batch,
    const float* __restrict__ partA, const float* __restrict__ partB,
    const float* __restrict__ segX,
    const int* __restrict__ first, const int* __restrict__ last,
    const float* __restrict__ Wv1, const float* __restrict__ bv1,
    const float* __restrict__ Wv2, const float* __restrict__ bv2,
    const float* __restrict__ Wp1, const float* __restrict__ bp1,
    const float* __restrict__ Wp2, const float* __restrict__ bp2,
    float* __restrict__ out) {
  __shared__ __align__(16) float bufA[HDIM];
  __shared__ __align__(16) float bufB[HDIM];
  __shared__ __align__(16) float part[8 * HDIM];  // viewed as [16][128] in L4
  const int t = threadIdx.x;
  const int g = blockIdx.x;

  float myb1 = 0.f, myb2 = 0.f, myb3 = 0.f, myb4 = 0.f;
  if (t < HDIM) {
    myb1 = bv1[t]; myb2 = bv2[t]; myb3 = bp1[t];
    // fused reduce (same order as before: segX, tiles asc, partA then partB)
    float s = segX[g * HDIM + t];
    int   f = first[g];
    if (f >= 0) {
      const int t0 = f >> 6, t1 = last[g] >> 6;
      for (int tl = t0; tl <= t1; ++tl) {
        if (batch[tl * 64] == g)      s += partA[(size_t)tl * HDIM + t];
        if (batch[tl * 64 + 63] == g) s += partB[(size_t)tl * HDIM + t];
      }
    }
    bufA[t] = s * 0.125f;
  }
  if (t < ODIM) myb4 = bp2[t];
  __syncthreads();

  mlp_layer256(bufA, bufB, part, Wv1, myb1, true,  t);
  mlp_layer256(bufB, bufA, part, Wv2, myb2, false, t);
  mlp_layer256(bufA, bufB, part, Wp1, myb3, true,  t);

  // layer 4: out[g] = bufB @ Wp2 + bp2 (O=128). 16 k-chunks x 32 col-quads.
  {
    const int w  = t >> 5;
    const int jq = t & 31;
    f32x4 av[4];                         // 16 a-values in registers
#pragma unroll
    for (int i = 0; i < 4; ++i) av[i] = *(const f32x4*)&bufB[w * 16 + i * 4];
    f32x4 acc = {0.f, 0.f, 0.f, 0.f};
    const float4* wrow = (const float4*)(Wp2 + (size_t)w * 16 * ODIM) + jq;
#pragma unroll
    for (int k = 0; k < 16; ++k) {
      float  a  = av[k >> 2][k & 3];
      float4 ww = wrow[(size_t)k * (ODIM / 4)];
      acc[0] += a * ww.x; acc[1] += a * ww.y;
      acc[2] += a * ww.z; acc[3] += a * ww.w;
    }
    *(f32x4*)&part[w * ODIM + jq * 4] = acc;
    __syncthreads();
    if (t < ODIM) {
      float v = myb4;
#pragma unroll
      for (int r = 0; r < 16; ++r) v += part[r * ODIM + t];
      out[g * ODIM + t] = v;
    }
  }
}

// ---------------------------------------------------------------------------
extern "C" void kernel_launch(void* const* d_in, const int* in_sizes, int n_in,
                              void* d_out, int out_size, void* d_ws, size_t ws_size,
                              hipStream_t stream) {
  const float* x     = (const float*)d_in[0];
  // d_in[1] = edge_index : unused by the reference
  const int*   batch = (const int*)d_in[2];
  const float* W_enc = (const float*)d_in[3];
  const float* b_enc = (const float*)d_in[4];
  const float* W_v1  = (const float*)d_in[5];
  const float* b_v1  = (const float*)d_in[6];
  const float* W_v2  = (const float*)d_in[7];
  const float* b_v2  = (const float*)d_in[8];
  const float* W_p1  = (const float*)d_in[9];
  const float* b_p1  = (const float*)d_in[10];
  const float* W_p2  = (const float*)d_in[11];
  const float* b_p2  = (const float*)d_in[12];
  float* out = (float*)d_out;

  float*  segX  = (float*)((char*)d_ws + WS_SEGX);
  __bf16* Bsw   = (__bf16*)((char*)d_ws + WS_BSW);
  int*    first = (int*)((char*)d_ws + WS_FIRST);
  int*    last  = (int*)((char*)d_ws + WS_LAST);
  float*  partA = (float*)((char*)d_ws + WS_PARTA);
  float*  partB = (float*)((char*)d_ws + WS_PARTB);

  prep_kernel<<<4, 256, 0, stream>>>(W_enc, Bsw, segX, first);
  bound_kernel<<<100, 1024, 0, stream>>>(batch, first, last);
  enc_gemm<<<NTILES, 512, 0, stream>>>(x, batch, Bsw, b_enc, partA, partB, segX);
  mlp_kernel<<<NGRAPH, 512, 0, stream>>>(batch, partA, partB, segX, first, last,
                                         W_v1, b_v1, W_v2, b_v2,
                                         W_p1, b_p1, W_p2, b_p2, out);
}